// Round 8
// baseline (387.546 us; speedup 1.0000x reference)
//
#include <hip/hip_runtime.h>

// SIZE = (D,H,W) = (160,192,160), B=2, C=2.
#define DD 160
#define HH 192
#define WW 160
#define SP (DD * HH * WW)
#define NB 2
#define NC 2

// Pure-gather kernel: NO LDS, NO barriers. Each thread produces 4
// consecutive x outputs for BOTH channels (shared corner offsets/weights).
// Trilinear corners come straight from L1/L2/L3 — the per-tile src
// working set (~26 KB) is L1-resident and src (78.6 MB) is L3-resident,
// so caches replace the staged-LDS structure whose barrier/vmcnt drains
// capped VALUBusy at ~40% across R4-R7.
#define TX 32
#define TY 8
#define TZ 4
#define NTX 5
#define NTY 24
#define NTZ 40
#define NTILES (NTX * NTY * NTZ * NB)   // 9600 blocks
#define PER_XCD (NTILES / 8)            // 1200

typedef float v2f __attribute__((ext_vector_type(2)));
typedef float v4f __attribute__((ext_vector_type(4)));

__device__ __forceinline__ v4f ld4_nt(const float* p) {
    return __builtin_nontemporal_load(reinterpret_cast<const v4f*>(p));
}
__device__ __forceinline__ void st4_nt(float* p, v4f v) {
    __builtin_nontemporal_store(v, reinterpret_cast<v4f*>(p));
}
__device__ __forceinline__ v2f ld2g(const float* p) {
    return *reinterpret_cast<const v2f*>(p);
}
__device__ __forceinline__ float pick(v2f v, int i) { return i ? v.y : v.x; }

// General single-channel trilinear gather (any displacement): clamped
// indices + zero-weight masks, matches reference padding_mode='zeros'.
// Used only as the rare (~0.3%) fallback on interior tiles.
__device__ __forceinline__ float sample_global1(
    const float* __restrict__ s,
    int x, int y, int z, float dx, float dy, float dz)
{
    float sx = (float)x + dx, sy = (float)y + dy, sz = (float)z + dz;
    float xf = floorf(sx), yf = floorf(sy), zf = floorf(sz);
    float fx = sx - xf, fy = sy - yf, fz = sz - zf;
    int x0 = (int)xf, y0 = (int)yf, z0 = (int)zf;
    int x1 = x0 + 1, y1 = y0 + 1, z1 = z0 + 1;

    float wx0 = (x0 >= 0 && x0 < WW) ? (1.0f - fx) : 0.0f;
    float wx1 = (x1 >= 0 && x1 < WW) ? fx : 0.0f;
    float wy0 = (y0 >= 0 && y0 < HH) ? (1.0f - fy) : 0.0f;
    float wy1 = (y1 >= 0 && y1 < HH) ? fy : 0.0f;
    float wz0 = (z0 >= 0 && z0 < DD) ? (1.0f - fz) : 0.0f;
    float wz1 = (z1 >= 0 && z1 < DD) ? fz : 0.0f;

    int p  = min(max(x0, 0), WW - 2);
    int i0 = min(max(x0, 0), WW - 1) - p;
    int i1 = min(max(x1, 0), WW - 1) - p;
    int cy0 = min(max(y0, 0), HH - 1), cy1 = min(max(y1, 0), HH - 1);
    int cz0 = min(max(z0, 0), DD - 1), cz1 = min(max(z1, 0), DD - 1);

    int o00 = (cz0 * HH + cy0) * WW + p;
    int o01 = (cz0 * HH + cy1) * WW + p;
    int o10 = (cz1 * HH + cy0) * WW + p;
    int o11 = (cz1 * HH + cy1) * WW + p;

    v2f c00 = ld2g(s + o00);
    v2f c01 = ld2g(s + o01);
    v2f c10 = ld2g(s + o10);
    v2f c11 = ld2g(s + o11);

    float r;
    r  = (wz0 * wy0) * (wx0 * pick(c00, i0) + wx1 * pick(c00, i1));
    r += (wz0 * wy1) * (wx0 * pick(c01, i0) + wx1 * pick(c01, i1));
    r += (wz1 * wy0) * (wx0 * pick(c10, i0) + wx1 * pick(c10, i1));
    r += (wz1 * wy1) * (wx0 * pick(c11, i0) + wx1 * pick(c11, i1));
    return r;
}

// Both-channel trilinear gather with per-axis interiority specialization.
// IX : tile is x-interior AND |dx|<4 -> x indices provably in [0,158];
//      skip x masks/clamps.  IYZ likewise for y and z.
// For a fully-edge tile (<false,false>) this is the general masked path
// valid for ANY displacement (no fallback needed).
template<bool IX, bool IYZ>
__device__ __forceinline__ void sample_fast(
    const float* __restrict__ s0, float sx, float sy, float sz,
    float& r0, float& r1)
{
    float xf = floorf(sx), yf = floorf(sy), zf = floorf(sz);
    float fx = sx - xf, fy = sy - yf, fz = sz - zf;
    int ix = (int)xf, iy = (int)yf, iz = (int)zf;

    float wx0, wx1; int px, i0, i1;
    if (IX) {
        px = ix; i0 = 0; i1 = 1; wx0 = 1.0f - fx; wx1 = fx;
    } else {
        wx0 = (ix >= 0  && ix < WW)     ? (1.0f - fx) : 0.0f;
        wx1 = (ix >= -1 && ix < WW - 1) ? fx          : 0.0f;
        px = min(max(ix, 0), WW - 2);
        i0 = min(max(ix, 0), WW - 1) - px;
        i1 = min(max(ix + 1, 0), WW - 1) - px;
    }
    float wy0, wy1, wz0, wz1; int py0, py1, pz0, pz1;
    if (IYZ) {
        py0 = iy; py1 = iy + 1; wy0 = 1.0f - fy; wy1 = fy;
        pz0 = iz; pz1 = iz + 1; wz0 = 1.0f - fz; wz1 = fz;
    } else {
        wy0 = (iy >= 0  && iy < HH)     ? (1.0f - fy) : 0.0f;
        wy1 = (iy >= -1 && iy < HH - 1) ? fy          : 0.0f;
        py0 = min(max(iy, 0), HH - 1);
        py1 = min(max(iy + 1, 0), HH - 1);
        wz0 = (iz >= 0  && iz < DD)     ? (1.0f - fz) : 0.0f;
        wz1 = (iz >= -1 && iz < DD - 1) ? fz          : 0.0f;
        pz0 = min(max(iz, 0), DD - 1);
        pz1 = min(max(iz + 1, 0), DD - 1);
    }

    int o00 = (pz0 * HH + py0) * WW + px;
    int o01 = (pz0 * HH + py1) * WW + px;
    int o10 = (pz1 * HH + py0) * WW + px;
    int o11 = (pz1 * HH + py1) * WW + px;

    v2f A00 = ld2g(s0 + o00), A01 = ld2g(s0 + o01);
    v2f A10 = ld2g(s0 + o10), A11 = ld2g(s0 + o11);
    v2f B00 = ld2g(s0 + SP + o00), B01 = ld2g(s0 + SP + o01);
    v2f B10 = ld2g(s0 + SP + o10), B11 = ld2g(s0 + SP + o11);

    float w00 = wz0 * wy0, w01 = wz0 * wy1, w10 = wz1 * wy0, w11 = wz1 * wy1;
    #define XL(v) (wx0 * pick(v, i0) + wx1 * pick(v, i1))
    r0 = w00 * XL(A00) + w01 * XL(A01) + w10 * XL(A10) + w11 * XL(A11);
    r1 = w00 * XL(B00) + w01 * XL(B01) + w10 * XL(B10) + w11 * XL(B11);
    #undef XL
}

// 4 samples x 2 channels per thread.
template<bool IX, bool IYZ>
__device__ __forceinline__ void compute_tile(
    const float* __restrict__ sb, int x, int y, int z,
    v4f dxv, v4f dyv, v4f dzv, float* __restrict__ op)
{
    float a0[4], a1[4];
    #pragma unroll
    for (int j = 0; j < 4; ++j) {
        float dx = dxv[j], dy = dyv[j], dz = dzv[j];
        bool ok = true;    // interiority precondition per specialized axis
        if (IX)  ok = (dx >= -4.0f) & (dx < 4.0f);
        if (IYZ) ok = ok & (dy >= -4.0f) & (dy < 4.0f) &
                          (dz >= -4.0f) & (dz < 4.0f);
        if (ok) {
            sample_fast<IX, IYZ>(sb, (float)(x + j) + dx, (float)y + dy,
                                 (float)z + dz, a0[j], a1[j]);
        } else {           // rare (~0.3%); never taken for <false,false>
            a0[j] = sample_global1(sb,      x + j, y, z, dx, dy, dz);
            a1[j] = sample_global1(sb + SP, x + j, y, z, dx, dy, dz);
        }
    }
    v4f o0 = {a0[0], a0[1], a0[2], a0[3]};
    v4f o1 = {a1[0], a1[1], a1[2], a1[3]};
    st4_nt(op, o0);
    st4_nt(op + SP, o1);
}

// 24 waves/CU (6 blocks x 4 waves), VGPR cap 85 — slack so nothing spills
// (check: WRITE_SIZE must be exactly 76,800 KB).
__global__ __launch_bounds__(256, 6) void st_warp_kernel(
    const float* __restrict__ src,   // [B, C, D, H, W]
    const float* __restrict__ flow,  // [B, 3, D, H, W]
    float* __restrict__ out)         // [B, C, D, H, W]
{
    int u   = blockIdx.x;
    int tl  = (u & 7) * PER_XCD + (u >> 3);   // XCD-contiguous tile ranges
    int tx  = tl % NTX;  int t2 = tl / NTX;
    int ty  = t2 % NTY;  int t3 = t2 / NTY;
    int tz  = t3 % NTZ;  int b  = t3 / NTZ;
    int X0 = tx * TX, Y0 = ty * TY, Z0 = tz * TZ;
    int tid = threadIdx.x;

    int xi = (tid & 7) << 2;         // x: 0..28 step 4
    int rr = tid >> 3;               // 0..31
    int yl = rr & 7, zl = rr >> 3;   // y 0..7, z 0..3
    int x = X0 + xi, y = Y0 + yl, z = Z0 + zl;

    int go = (z * HH + y) * WW + x;
    const float* sb = src + b * NC * SP;
    const float* fp = flow + b * 3 * SP + go;
    float* op = out + b * NC * SP + go;

    v4f dxv = ld4_nt(fp);
    v4f dyv = ld4_nt(fp + SP);
    v4f dzv = ld4_nt(fp + 2 * SP);

    // Interiority: +-4 halo fits inside the volume on the given axes.
    bool xin  = (tx >= 1) & (tx <= 3);
    bool yzin = (ty >= 1) & (ty <= 22) & (tz >= 1) & (tz <= 38);

    if (xin & yzin)      compute_tile<true,  true >(sb, x, y, z, dxv, dyv, dzv, op);
    else if (xin)        compute_tile<true,  false>(sb, x, y, z, dxv, dyv, dzv, op);
    else if (yzin)       compute_tile<false, true >(sb, x, y, z, dxv, dyv, dzv, op);
    else                 compute_tile<false, false>(sb, x, y, z, dxv, dyv, dzv, op);
}

extern "C" void kernel_launch(void* const* d_in, const int* in_sizes, int n_in,
                              void* d_out, int out_size, void* d_ws, size_t ws_size,
                              hipStream_t stream) {
    const float* src  = (const float*)d_in[0];
    const float* flow = (const float*)d_in[1];
    float* out = (float*)d_out;

    st_warp_kernel<<<NTILES, 256, 0, stream>>>(src, flow, out);
}

// Round 9
// 319.298 us; speedup vs baseline: 1.2137x; 1.2137x over previous
//
#include <hip/hip_runtime.h>

// SIZE = (D,H,W) = (160,192,160), B=2, C=2.
#define DD 160
#define HH 192
#define WW 160
#define SP (DD * HH * WW)
#define NB 2
#define NC 2

// Persistent blocks, 1024 threads, 2 voxels/thread (x-pair), BOTH channels
// per voxel from channel-INTERLEAVED LDS (one ds_read2_b64 per corner ->
// half the LDS instrs of the split-channel scheme, weights shared across
// channels). Double-buffered across TILES, ONE barrier per tile.
// Staging is register-based (T14 async-split: issue loads early, ds_write
// late) because global_load_lds cannot produce an interleaved layout.
// 2x72 KB LDS -> 1 block/CU x 16 waves; VGPR cap 128 -> no spill.
#define TX 32
#define TY 8
#define TZ 8
#define RXW 40                 // x: [X0-4, X0+35]  supports dx in [-4,4)
#define RYH 15                 // y: [Y0-3, Y0+11]  supports dy in [-3,4)
#define RZD 15                 // z: [Z0-3, Z0+11]  supports dz in [-3,4)
#define REGC (RZD * RYH * RXW) // 9000 voxels; interleaved buffer = 72,000 B
#define NQUAD (REGC / 4)       // 2250 4-voxel row quads
#define NITER 3                // ceil(2250/1024)
#define NTHR 1024

#define NTX 5
#define NTY 24
#define NTZ 20
#define NTILES (NTX * NTY * NTZ * NB)   // 4800 tiles
#define TPX (NTILES / 8)                // 600 tiles per XCD
#define NBLK 256                        // persistent: 1 block/CU
#define SLOTS (NBLK / 8)                // 32 slots per XCD

typedef float v2f __attribute__((ext_vector_type(2)));
typedef float v4f __attribute__((ext_vector_type(4)));

__device__ __forceinline__ v2f ld2_nt(const float* p) {
    return __builtin_nontemporal_load(reinterpret_cast<const v2f*>(p));
}
__device__ __forceinline__ void st2_nt(float* p, v2f v) {
    __builtin_nontemporal_store(v, reinterpret_cast<v2f*>(p));
}
__device__ __forceinline__ v2f ld2g(const float* p) {
    return *reinterpret_cast<const v2f*>(p);
}
__device__ __forceinline__ float pick(v2f v, int i) { return i ? v.y : v.x; }
__device__ __forceinline__ v2f s2(float f) { v2f v = {f, f}; return v; }

// Rare fallback (~0.3%): displacement outside staged halo — full global
// trilinear, single channel.
__device__ __forceinline__ float sample_global1(
    const float* __restrict__ s,
    int x, int y, int z, float dx, float dy, float dz)
{
    float sx = (float)x + dx, sy = (float)y + dy, sz = (float)z + dz;
    float xf = floorf(sx), yf = floorf(sy), zf = floorf(sz);
    float fx = sx - xf, fy = sy - yf, fz = sz - zf;
    int x0 = (int)xf, y0 = (int)yf, z0 = (int)zf;
    int x1 = x0 + 1, y1 = y0 + 1, z1 = z0 + 1;

    float wx0 = (x0 >= 0 && x0 < WW) ? (1.0f - fx) : 0.0f;
    float wx1 = (x1 >= 0 && x1 < WW) ? fx : 0.0f;
    float wy0 = (y0 >= 0 && y0 < HH) ? (1.0f - fy) : 0.0f;
    float wy1 = (y1 >= 0 && y1 < HH) ? fy : 0.0f;
    float wz0 = (z0 >= 0 && z0 < DD) ? (1.0f - fz) : 0.0f;
    float wz1 = (z1 >= 0 && z1 < DD) ? fz : 0.0f;

    int p  = min(max(x0, 0), WW - 2);
    int i0 = min(max(x0, 0), WW - 1) - p;
    int i1 = min(max(x1, 0), WW - 1) - p;
    int cy0 = min(max(y0, 0), HH - 1), cy1 = min(max(y1, 0), HH - 1);
    int cz0 = min(max(z0, 0), DD - 1), cz1 = min(max(z1, 0), DD - 1);

    int o00 = (cz0 * HH + cy0) * WW + p;
    int o01 = (cz0 * HH + cy1) * WW + p;
    int o10 = (cz1 * HH + cy0) * WW + p;
    int o11 = (cz1 * HH + cy1) * WW + p;

    v2f c00 = ld2g(s + o00);
    v2f c01 = ld2g(s + o01);
    v2f c10 = ld2g(s + o10);
    v2f c11 = ld2g(s + o11);

    float r;
    r  = (wz0 * wy0) * (wx0 * pick(c00, i0) + wx1 * pick(c00, i1));
    r += (wz0 * wy1) * (wx0 * pick(c01, i0) + wx1 * pick(c01, i1));
    r += (wz1 * wy0) * (wx0 * pick(c10, i0) + wx1 * pick(c10, i1));
    r += (wz1 * wy1) * (wx0 * pick(c11, i0) + wx1 * pick(c11, i1));
    return r;
}

// ---- Register staging of one tile's BOTH-channel interleaved region ----
// Quad q covers region voxels 4q..4q+3 of one row; LDS floats 8q..8q+7
// hold c0(v),c1(v) interleaved. Issue loads early; write LDS late (T14).
//
// EDGE NOTE: x-edge quads (only lxc=0 at X0=0 / lxc=9 at X0=128) are FULLY
// out-of-volume; y/z clamps replicate rows. Out-of-volume region cells are
// only ever read with zero weight (masks test *volume* coords), so the
// clamped garbage never contributes — clamp exists only for address safety.
__device__ __forceinline__ void stage_issue(
    const float* __restrict__ cb, int X0, int Y0, int Z0, int tid,
    v4f* A, v4f* B, int* ad)
{
    #pragma unroll
    for (int i = 0; i < NITER; ++i) {
        int q = tid + i * NTHR;
        if (i < NITER - 1 || q < NQUAD) {
            int r  = q / 10;  int xq = q - r * 10;    // 10 quads per row
            int lz = r / 15;  int ly = r - lz * 15;
            int mz = min(max(Z0 - 3 + lz, 0), DD - 1);
            int my = min(max(Y0 - 3 + ly, 0), HH - 1);
            int mx = min(max(X0 - 4 + xq * 4, 0), WW - 4);  // 16B-aligned
            const float* p = cb + (mz * HH + my) * WW + mx;
            A[i] = *reinterpret_cast<const v4f*>(p);        // channel 0
            B[i] = *reinterpret_cast<const v4f*>(p + SP);   // channel 1
            ad[i] = 8 * q;
        } else {
            ad[i] = -1;
        }
    }
}

__device__ __forceinline__ void stage_write(
    float* __restrict__ sbuf, const v4f* A, const v4f* B, const int* ad)
{
    #pragma unroll
    for (int i = 0; i < NITER; ++i) {
        if (ad[i] >= 0) {
            v4f w0 = {A[i].x, B[i].x, A[i].y, B[i].y};
            v4f w1 = {A[i].z, B[i].z, A[i].w, B[i].w};
            *reinterpret_cast<v4f*>(&sbuf[ad[i]])     = w0;
            *reinterpret_cast<v4f*>(&sbuf[ad[i] + 4]) = w1;
        }
    }
}

// Both-channel trilinear sample from the interleaved region.
// Each corner: c0(x0),c1(x0),c0(x1),c1(x1) = two adjacent 8B LDS reads
// (-> one ds_read2_b64). Weights computed ONCE, applied to both channels
// via v2f lanes. INTERIOR skips the provably-pass boundary masks.
template<bool INTERIOR>
__device__ __forceinline__ v2f sample_il(
    const float* __restrict__ sbuf,
    float lx, float ly, float lz, int rx0, int ry0, int rz0)
{
    float xf = floorf(lx), yf = floorf(ly), zf = floorf(lz);
    float fx = lx - xf, fy = ly - yf, fz = lz - zf;
    int ix = (int)xf, iy = (int)yf, iz = (int)zf;

    float wx0, wx1, wy0, wy1, wz0, wz1;
    if (INTERIOR) {
        wx0 = 1.0f - fx; wx1 = fx;
        wy0 = 1.0f - fy; wy1 = fy;
        wz0 = 1.0f - fz; wz1 = fz;
    } else {
        int vx0 = ix + rx0, vy0 = iy + ry0, vz0 = iz + rz0;
        wx0 = (vx0 >= 0  && vx0 < WW)     ? (1.0f - fx) : 0.0f;
        wx1 = (vx0 >= -1 && vx0 < WW - 1) ? fx          : 0.0f;
        wy0 = (vy0 >= 0  && vy0 < HH)     ? (1.0f - fy) : 0.0f;
        wy1 = (vy0 >= -1 && vy0 < HH - 1) ? fy          : 0.0f;
        wz0 = (vz0 >= 0  && vz0 < DD)     ? (1.0f - fz) : 0.0f;
        wz1 = (vz0 >= -1 && vz0 < DD - 1) ? fz          : 0.0f;
    }

    const float* pB = sbuf + 2 * ((iz * RYH + iy) * RXW + ix);
    v2f A00 = *(const v2f*)(pB);
    v2f B00 = *(const v2f*)(pB + 2);
    v2f A01 = *(const v2f*)(pB + 2 * RXW);
    v2f B01 = *(const v2f*)(pB + 2 * RXW + 2);
    const float* pC = pB + 2 * RYH * RXW;
    v2f A10 = *(const v2f*)(pC);
    v2f B10 = *(const v2f*)(pC + 2);
    v2f A11 = *(const v2f*)(pC + 2 * RXW);
    v2f B11 = *(const v2f*)(pC + 2 * RXW + 2);

    v2f c00 = s2(wx0) * A00 + s2(wx1) * B00;
    v2f c01 = s2(wx0) * A01 + s2(wx1) * B01;
    v2f c10 = s2(wx0) * A10 + s2(wx1) * B10;
    v2f c11 = s2(wx0) * A11 + s2(wx1) * B11;
    v2f m0  = s2(wy0) * c00 + s2(wy1) * c01;
    v2f m1  = s2(wy0) * c10 + s2(wy1) * c11;
    return s2(wz0) * m0 + s2(wz1) * m1;   // .x = c0, .y = c1
}

struct Geo {
    int X0, Y0, Z0;
    int x, y, z;          // this thread's coords (x = first of 2)
    bool interior;        // region strictly inside the volume
    const float* sb;      // src channel-0 base for this batch
    const float* fp;      // flow pointer for this thread
    float* op;            // out pointer (channel 0) for this thread
};

__device__ __forceinline__ Geo decode_tile(
    int tl, const float* src, const float* flow, float* out,
    int xi, int yl, int zl)
{
    Geo g;
    int tx = tl % NTX;  int t2 = tl / NTX;
    int ty = t2 % NTY;  int t3 = t2 / NTY;
    int tz = t3 % NTZ;  int b  = t3 / NTZ;
    g.X0 = tx * TX; g.Y0 = ty * TY; g.Z0 = tz * TZ;
    g.interior = (tx >= 1) & (tx <= 3) &
                 (ty >= 1) & (ty <= 22) &
                 (tz >= 1) & (tz <= 18);
    g.x = g.X0 + xi; g.y = g.Y0 + yl; g.z = g.Z0 + zl;
    int go = (g.z * HH + g.y) * WW + g.x;
    g.sb = src + b * NC * SP;
    g.fp = flow + b * 3 * SP + go;
    g.op = out + b * NC * SP + go;
    return g;
}

// 2 voxels x 2 channels per thread, both channels per LDS pass.
template<bool INTERIOR>
__device__ __forceinline__ void compute_store(
    const float* __restrict__ sbuf, const Geo& g,
    v2f dxv, v2f dyv, v2f dzv, int xi, int yl, int zl)
{
    const int rx0 = g.X0 - 4, ry0 = g.Y0 - 3, rz0 = g.Z0 - 3;
    v2f a[2];
    #pragma unroll
    for (int j = 0; j < 2; ++j) {
        float dx = dxv[j], dy = dyv[j], dz = dzv[j];
        bool inH = (dx >= -4.0f) & (dx < 4.0f) &
                   (dy >= -3.0f) & (dy < 4.0f) &
                   (dz >= -3.0f) & (dz < 4.0f);
        if (inH) {
            float lx = (float)(xi + j + 4) + dx;
            float ly = (float)(yl + 3) + dy;
            float lz = (float)(zl + 3) + dz;
            a[j] = sample_il<INTERIOR>(sbuf, lx, ly, lz, rx0, ry0, rz0);
        } else {
            a[j].x = sample_global1(g.sb,      g.x + j, g.y, g.z, dx, dy, dz);
            a[j].y = sample_global1(g.sb + SP, g.x + j, g.y, g.z, dx, dy, dz);
        }
    }
    v2f o0 = {a[0].x, a[1].x};
    v2f o1 = {a[0].y, a[1].y};
    st2_nt(g.op, o0);
    st2_nt(g.op + SP, o1);
}

// 1 block/CU (144 KB LDS), 16 waves, VGPR cap 128 -> no spill
// (check: WRITE_SIZE must be exactly 76,800 KB).
__global__ __launch_bounds__(NTHR, 4) void st_warp_kernel(
    const float* __restrict__ src,   // [B, C, D, H, W]
    const float* __restrict__ flow,  // [B, 3, D, H, W]
    float* __restrict__ out)         // [B, C, D, H, W]
{
    __shared__ float sX[2 * REGC];   // tile-parity buffer 0 (72,000 B)
    __shared__ float sY[2 * REGC];   // tile-parity buffer 1 (72,000 B)

    int u    = blockIdx.x;
    int xcd  = u & 7;                // XCD-chunked tile ranges
    int slot = u >> 3;               // 0..31 within XCD
    int tid  = threadIdx.x;

    int xi = (tid & 15) << 1;        // x: 0..30 step 2
    int yl = (tid >> 4) & 7;         // y: 0..7
    int zl = tid >> 7;               // z: 0..7

    int nt = (TPX - slot + SLOTS - 1) / SLOTS;   // 18 or 19 tiles
    int tl = xcd * TPX + slot;

    // ---- Prologue: stage tile 0 (both channels, interleaved) ----
    Geo g = decode_tile(tl, src, flow, out, xi, yl, zl);
    v4f A[NITER], B[NITER]; int ad[NITER];
    stage_issue(g.sb, g.X0, g.Y0, g.Z0, tid, A, B, ad);
    v2f dxv = ld2_nt(g.fp);
    v2f dyv = ld2_nt(g.fp + SP);
    v2f dzv = ld2_nt(g.fp + 2 * SP);
    stage_write(sX, A, B, ad);
    __syncthreads();

    float* front = sX;
    float* back  = sY;

    for (int t = 0; t < nt; ++t) {
        bool more = (t + 1 < nt);            // block-uniform
        Geo gn = g;
        v2f nxv = dxv, nyv = dyv, nzv = dzv;
        if (more) {
            // Issue next tile's loads BEFORE compute: HBM latency hides
            // under this tile's full compute phase (T14 async-split).
            gn = decode_tile(tl + (t + 1) * SLOTS, src, flow, out, xi, yl, zl);
            stage_issue(gn.sb, gn.X0, gn.Y0, gn.Z0, tid, A, B, ad);
            nxv = ld2_nt(gn.fp);
            nyv = ld2_nt(gn.fp + SP);
            nzv = ld2_nt(gn.fp + 2 * SP);
        }

        if (g.interior)
            compute_store<true >(front, g, dxv, dyv, dzv, xi, yl, zl);
        else
            compute_store<false>(front, g, dxv, dyv, dzv, xi, yl, zl);

        if (more)
            stage_write(back, A, B, ad);     // waits the prefetch, writes LDS

        __syncthreads();                     // ONE barrier per tile
        float* tmp = front; front = back; back = tmp;
        g = gn; dxv = nxv; dyv = nyv; dzv = nzv;
    }
}

extern "C" void kernel_launch(void* const* d_in, const int* in_sizes, int n_in,
                              void* d_out, int out_size, void* d_ws, size_t ws_size,
                              hipStream_t stream) {
    const float* src  = (const float*)d_in[0];
    const float* flow = (const float*)d_in[1];
    float* out = (float*)d_out;

    st_warp_kernel<<<NBLK, NTHR, 0, stream>>>(src, flow, out);
}